// Round 3
// baseline (87.949 us; speedup 1.0000x reference)
//
#include <hip/hip_runtime.h>
#include <hip/hip_bf16.h>

// Problem constants (match reference)
#define PB 8          // batches
#define PS 2048       // sequence length
#define PN 4096       // spans per batch
#define PD 256        // feature dim
#define CHUNK 64
#define NCHUNK (PS / CHUNK)   // 32
// MAX_W = 16: starts in [0, S-16), width in [0,15] -> end+1 <= 2047 < PS,
// so the prefix-sum table needs only PS rows (P[b,s,:] = sum of rows [0,s)).

// ---------------------------------------------------------------------------
// K1: per-(batch, chunk) column sums. grid = PB*NCHUNK blocks, 256 thr (d).
// blockIdx & 7 = batch -> XCD-local.
__global__ __launch_bounds__(256) void k_chunksum(const float* __restrict__ seq,
                                                  float* __restrict__ csum) {
    const int b = blockIdx.x & 7;
    const int c = blockIdx.x >> 3;
    const int d = threadIdx.x;
    const float* p = seq + (((size_t)b * PS + (size_t)c * CHUNK) * PD) + d;
    float s = 0.f;
    #pragma unroll 16
    for (int i = 0; i < CHUNK; ++i) s += p[(size_t)i * PD];
    csum[((size_t)b * NCHUNK + c) * PD + d] = s;
}

// ---------------------------------------------------------------------------
// K2: exclusive scan of the NCHUNK chunk sums per (b, d). grid = PB blocks.
// All 32 loads issued up-front (full MLP), then the register-resident scan.
__global__ __launch_bounds__(256) void k_chunkscan(const float* __restrict__ csum,
                                                   float* __restrict__ coff) {
    const int b = blockIdx.x;
    const int d = threadIdx.x;
    float v[NCHUNK];
    #pragma unroll
    for (int c = 0; c < NCHUNK; ++c)
        v[c] = csum[((size_t)b * NCHUNK + c) * PD + d];
    float run = 0.f;
    #pragma unroll
    for (int c = 0; c < NCHUNK; ++c) {
        coff[((size_t)b * NCHUNK + c) * PD + d] = run;
        run += v[c];
    }
}

// ---------------------------------------------------------------------------
// K3: write P rows. Each (b, chunk) block streams its 64 rows:
// P[row i] = running; running += seq[row i].
__global__ __launch_bounds__(256) void k_writeP(const float* __restrict__ seq,
                                                const float* __restrict__ coff,
                                                float* __restrict__ P) {
    const int b = blockIdx.x & 7;
    const int c = blockIdx.x >> 3;
    const int d = threadIdx.x;
    const size_t rowbase = ((size_t)b * PS + (size_t)c * CHUNK) * PD + d;
    const float* ps = seq + rowbase;
    float*       pp = P   + rowbase;
    float run = coff[((size_t)b * NCHUNK + c) * PD + d];
    #pragma unroll 8
    for (int i = 0; i < CHUNK; ++i) {
        const float x = ps[(size_t)i * PD];   // load prefetches ahead of dep chain
        pp[(size_t)i * PD] = run;
        run += x;
    }
}

// ---------------------------------------------------------------------------
// K4: gather. One wave per span; lane owns float4 [4*lane, 4*lane+4).
// out = (P[end+1] - P[start]) / (width+1). 2 KiB read + 1 KiB write per span.
__global__ __launch_bounds__(256) void k_gather(const float* __restrict__ P,
                                               const int*   __restrict__ spans,
                                               float*       __restrict__ out) {
    const int b       = blockIdx.x & 7;            // batch == XCD
    const int blk     = blockIdx.x >> 3;
    const int span_ib = (blk << 2) | (threadIdx.x >> 6);
    const int span    = (b << 12) | span_ib;
    const int lane    = threadIdx.x & 63;

    const int2 se = ((const int2*)spans)[span];    // x=start, y=end (inclusive)
    const float inv = 1.0f / (float)(se.y - se.x + 1);

    const float* Pb = P + ((size_t)b * PS) * PD + (lane << 2);
    const float4 p0 = *(const float4*)(Pb + (size_t)se.x       * PD);
    const float4 p1 = *(const float4*)(Pb + (size_t)(se.y + 1) * PD);

    float4 r;
    r.x = (p1.x - p0.x) * inv;
    r.y = (p1.y - p0.y) * inv;
    r.z = (p1.z - p0.z) * inv;
    r.w = (p1.w - p0.w) * inv;

    *(float4*)(out + (size_t)span * PD + (lane << 2)) = r;
}

extern "C" void kernel_launch(void* const* d_in, const int* in_sizes, int n_in,
                              void* d_out, int out_size, void* d_ws, size_t ws_size,
                              hipStream_t stream) {
    const float* seq   = (const float*)d_in[0];   // (B,S,D) f32
    const int*   spans = (const int*)d_in[1];     // (B,N,2) i32
    float*       out   = (float*)d_out;           // (B,N,D) f32

    // Workspace layout (all re-written every launch; poison-safe):
    //   P    : PB*PS*PD floats     (16 MiB)
    //   csum : PB*NCHUNK*PD floats (256 KiB)
    //   coff : PB*NCHUNK*PD floats (256 KiB)
    float* P    = (float*)d_ws;
    float* csum = P    + (size_t)PB * PS * PD;
    float* coff = csum + (size_t)PB * NCHUNK * PD;

    k_chunksum <<<dim3(PB * NCHUNK), dim3(256), 0, stream>>>(seq, csum);
    k_chunkscan<<<dim3(PB),          dim3(256), 0, stream>>>(csum, coff);
    k_writeP   <<<dim3(PB * NCHUNK), dim3(256), 0, stream>>>(seq, coff, P);
    k_gather   <<<dim3(PB * PN / 4), dim3(256), 0, stream>>>(P, spans, out);
}